// Round 1
// baseline (441.705 us; speedup 1.0000x reference)
//
#include <hip/hip_runtime.h>
#include <math.h>

#define TLEN 2048
#define BSZ  4
#define EDIM 768
#define NH   12
#define HD   64

typedef __bf16 bf16;
typedef __bf16 bf16x8 __attribute__((ext_vector_type(8)));
typedef float  f32x4  __attribute__((ext_vector_type(4)));

__device__ __forceinline__ f32x4 mfma16(bf16x8 a, bf16x8 b, f32x4 c) {
  return __builtin_amdgcn_mfma_f32_16x16x32_bf16(a, b, c, 0, 0, 0);
}

// ---------------- workspace layout (bytes) ----------------
#define CT_OFF 0u
#define ST_OFF (256u * 1024u)
#define Q_OFF  (1024u * 1024u)
#define KB_OFF (Q_OFF + 0xC00000u)
#define V_OFF  (KB_OFF + 0xC00000u)
#define X_OFF  (V_OFF + 0xC00000u)

// ---------------- RoPE tables (fp64 for accurate large-arg sin) ----------------
__global__ void rope_tab_kernel(float* __restrict__ ct, float* __restrict__ st) {
  int i = blockIdx.x * 256 + threadIdx.x;   // grid exactly TLEN*32
  int t = i >> 5, j = i & 31;
  double ang = (double)t * pow(10000.0, -(double)j / 32.0);
  st[i] = (float)sin(ang);
  ct[i] = (float)cos(ang);
}

// ---------------- staging helpers: 128x32 bf16 tile, pad to 40 ----------------
__device__ __forceinline__ void stage_f32(const float* __restrict__ src, int ld,
                                          int row0, int col0, bf16 (*lds)[40], int tid) {
#pragma unroll
  for (int i = 0; i < 2; ++i) {
    int c = tid + 256 * i;          // 0..511
    int row = c >> 2, cc = (c & 3) << 3;
    const float* p = src + (size_t)(row0 + row) * ld + col0 + cc;
    float4 v0 = *reinterpret_cast<const float4*>(p);
    float4 v1 = *reinterpret_cast<const float4*>(p + 4);
    bf16x8 o;
    o[0] = (bf16)v0.x; o[1] = (bf16)v0.y; o[2] = (bf16)v0.z; o[3] = (bf16)v0.w;
    o[4] = (bf16)v1.x; o[5] = (bf16)v1.y; o[6] = (bf16)v1.z; o[7] = (bf16)v1.w;
    *reinterpret_cast<bf16x8*>(&lds[row][cc]) = o;
  }
}

__device__ __forceinline__ void stage_bf16(const bf16* __restrict__ src, int ld,
                                           int row0, int col0, bf16 (*lds)[40], int tid) {
#pragma unroll
  for (int i = 0; i < 2; ++i) {
    int c = tid + 256 * i;
    int row = c >> 2, cc = (c & 3) << 3;
    *reinterpret_cast<bf16x8*>(&lds[row][cc]) =
        *reinterpret_cast<const bf16x8*>(src + (size_t)(row0 + row) * ld + col0 + cc);
  }
}

// ---------------- GEMM C = X * Y^T (+bias) with mode-specific epilogue ----------------
// MODE 0: A = query fp32 [8192][768]; W = in_proj_weight [2304][768];
//         epilogue: split q/k/v, RoPE on q,k, fold 1/8 scale into q, write bf16 [B][H][T][HD]
// MODE 1: A = x bf16 [8192][768]; W = out_proj_weight [768][768]; epilogue: +bias -> fp32 out
template <int MODE>
__global__ __launch_bounds__(256) void gemm_bt(
    const float* __restrict__ Af, const bf16* __restrict__ Ab,
    const float* __restrict__ W, const float* __restrict__ bias,
    const float* __restrict__ ct, const float* __restrict__ st,
    bf16* __restrict__ qo, bf16* __restrict__ ko, bf16* __restrict__ vo,
    float* __restrict__ fo, int N, int K) {
  __shared__ __align__(16) bf16 As[128][40];
  __shared__ __align__(16) bf16 Bs[128][40];
  int tid = threadIdx.x;
  int lane = tid & 63, w = tid >> 6;
  int wr = w >> 1, wc = w & 1;
  int g = lane >> 4, cl = lane & 15;
  int bm = blockIdx.y, bn = blockIdx.x;

  f32x4 acc[4][4] = {};

  for (int kt = 0; kt < K; kt += 32) {
    if (MODE == 0) stage_f32(Af, K, bm * 128, kt, As, tid);
    else           stage_bf16(Ab, K, bm * 128, kt, As, tid);
    stage_f32(W, K, bn * 128, kt, Bs, tid);
    __syncthreads();
    bf16x8 af[4], bfr[4];
#pragma unroll
    for (int mi = 0; mi < 4; ++mi)
      af[mi] = *reinterpret_cast<const bf16x8*>(&As[wr * 64 + mi * 16 + cl][g * 8]);
#pragma unroll
    for (int ni = 0; ni < 4; ++ni)
      bfr[ni] = *reinterpret_cast<const bf16x8*>(&Bs[wc * 64 + ni * 16 + cl][g * 8]);
#pragma unroll
    for (int mi = 0; mi < 4; ++mi)
#pragma unroll
      for (int ni = 0; ni < 4; ++ni)
        acc[mi][ni] = mfma16(af[mi], bfr[ni], acc[mi][ni]);
    __syncthreads();
  }

  if (MODE == 0) {
#pragma unroll
    for (int mi = 0; mi < 4; ++mi) {
      int mbase = bm * 128 + wr * 64 + mi * 16 + 4 * g;  // multiple of 4; rows mbase..mbase+3
      int t = mbase >> 2;                                // same t for r=0..3, b = r
#pragma unroll
      for (int ni = 0; ni < 4; ++ni) {
        int f = bn * 128 + wc * 64 + ni * 16 + cl;
        int sec = f / EDIM;           // uniform per block (tile fits in one section)
        int f0 = f - sec * EDIM;
        int h = f0 >> 6, d = f0 & 63;
        float bv = bias[f];
        float vals[4];
#pragma unroll
        for (int r = 0; r < 4; ++r) vals[r] = acc[mi][ni][r] + bv;
        if (sec < 2) {
          int j = d >> 1;
          float cv = ct[t * 32 + j], sv = st[t * 32 + j];
          bf16* dst = (sec == 0) ? qo : ko;
#pragma unroll
          for (int r = 0; r < 4; ++r) {
            float other = __shfl_xor(vals[r], 1);
            float rv = (d & 1) ? (vals[r] * cv + other * sv)
                               : (vals[r] * cv - other * sv);
            if (sec == 0) rv *= 0.125f;   // fold 1/sqrt(hd) into q
            dst[(((size_t)r * NH + h) * TLEN + t) * HD + d] = (bf16)rv;
          }
        } else {
#pragma unroll
          for (int r = 0; r < 4; ++r)
            vo[(((size_t)r * NH + h) * TLEN + t) * HD + d] = (bf16)vals[r];
        }
      }
    }
  } else {
#pragma unroll
    for (int mi = 0; mi < 4; ++mi) {
      int mbase = bm * 128 + wr * 64 + mi * 16 + 4 * g;
#pragma unroll
      for (int ni = 0; ni < 4; ++ni) {
        int n = bn * 128 + wc * 64 + ni * 16 + cl;
        float bv = bias[n];
#pragma unroll
        for (int r = 0; r < 4; ++r)
          fo[(size_t)(mbase + r) * EDIM + n] = acc[mi][ni][r] + bv;
      }
    }
  }
}

// ---------------- flash attention: Q-tile 64 rows, K/V tiles of 64 ----------------
__global__ __launch_bounds__(256) void attn_kernel(
    const bf16* __restrict__ qa, const bf16* __restrict__ ka, const bf16* __restrict__ va,
    const float* __restrict__ mask, bf16* __restrict__ xo) {
  __shared__ __align__(16) bf16 Ks[64][72];
  __shared__ __align__(16) bf16 Vt[64][72];     // transposed V tile: Vt[d][s]
  __shared__ __align__(16) bf16 Ps[4][16][72];  // per-wave P strip
  int tid = threadIdx.x;
  int lane = tid & 63, w = tid >> 6;
  int g = lane >> 4, cl = lane & 15;
  int qt = blockIdx.x, bh = blockIdx.y;
  const bf16* qbh = qa + (size_t)bh * TLEN * HD;
  const bf16* kbh = ka + (size_t)bh * TLEN * HD;
  const bf16* vbh = va + (size_t)bh * TLEN * HD;
  int qrow0 = qt * 64 + w * 16;

  // hoist Q fragments (scale already folded in)
  bf16x8 qf0 = *reinterpret_cast<const bf16x8*>(qbh + (size_t)(qrow0 + cl) * HD + g * 8);
  bf16x8 qf1 = *reinterpret_cast<const bf16x8*>(qbh + (size_t)(qrow0 + cl) * HD + g * 8 + 32);

  f32x4 o[4] = {};
  float mrow[4], drow[4];
#pragma unroll
  for (int r = 0; r < 4; ++r) { mrow[r] = -1e30f; drow[r] = 0.f; }

  for (int sti = 0; sti < TLEN / 64; ++sti) {
    int s0 = sti * 64;
    // stage K tile [64][64]
#pragma unroll
    for (int i = 0; i < 2; ++i) {
      int c = tid + 256 * i;
      int row = c >> 3, cc = (c & 7) << 3;
      *reinterpret_cast<bf16x8*>(&Ks[row][cc]) =
          *reinterpret_cast<const bf16x8*>(kbh + (size_t)(s0 + row) * HD + cc);
    }
    // stage V transposed: Vt[d][s]
#pragma unroll
    for (int i = 0; i < 2; ++i) {
      int c = tid + 256 * i;
      int srow = c >> 3, d0 = (c & 7) << 3;
      bf16x8 vv = *reinterpret_cast<const bf16x8*>(vbh + (size_t)(s0 + srow) * HD + d0);
#pragma unroll
      for (int jj = 0; jj < 8; ++jj) Vt[d0 + jj][srow] = vv[jj];
    }
    __syncthreads();

    // S = Q * K^T  (both loaded with identical lane mapping -> layout-robust)
    f32x4 sc[4];
#pragma unroll
    for (int ni = 0; ni < 4; ++ni) {
      bf16x8 k0 = *reinterpret_cast<const bf16x8*>(&Ks[ni * 16 + cl][g * 8]);
      bf16x8 k1 = *reinterpret_cast<const bf16x8*>(&Ks[ni * 16 + cl][g * 8 + 32]);
      f32x4 z = {};
      z = mfma16(qf0, k0, z);
      z = mfma16(qf1, k1, z);
      sc[ni] = z;
    }

    // + mask, online softmax (rows r=4g+reg, cols = ni*16+cl)
    float pm[4];
#pragma unroll
    for (int r = 0; r < 4; ++r) pm[r] = -1e30f;
#pragma unroll
    for (int ni = 0; ni < 4; ++ni)
#pragma unroll
      for (int r = 0; r < 4; ++r) {
        int qr = qrow0 + 4 * g + r;
        float sv = sc[ni][r] + mask[(size_t)qr * TLEN + s0 + ni * 16 + cl];
        sc[ni][r] = sv;
        pm[r] = fmaxf(pm[r], sv);
      }
#pragma unroll
    for (int r = 0; r < 4; ++r) {
#pragma unroll
      for (int off = 1; off < 16; off <<= 1)
        pm[r] = fmaxf(pm[r], __shfl_xor(pm[r], off));
    }
    float alpha[4];
#pragma unroll
    for (int r = 0; r < 4; ++r) {
      float mn = fmaxf(mrow[r], pm[r]);
      alpha[r] = __expf(mrow[r] - mn);
      mrow[r] = mn;
    }
    float rs[4] = {0.f, 0.f, 0.f, 0.f};
#pragma unroll
    for (int ni = 0; ni < 4; ++ni)
#pragma unroll
      for (int r = 0; r < 4; ++r) {
        float p = __expf(sc[ni][r] - mrow[r]);
        sc[ni][r] = p;
        rs[r] += p;
      }
#pragma unroll
    for (int r = 0; r < 4; ++r) {
#pragma unroll
      for (int off = 1; off < 16; off <<= 1) rs[r] += __shfl_xor(rs[r], off);
      drow[r] = drow[r] * alpha[r] + rs[r];
    }
#pragma unroll
    for (int di = 0; di < 4; ++di)
#pragma unroll
      for (int r = 0; r < 4; ++r) o[di][r] *= alpha[r];

    // P -> LDS (wave-private), reload as A-fragments
#pragma unroll
    for (int ni = 0; ni < 4; ++ni)
#pragma unroll
      for (int r = 0; r < 4; ++r)
        Ps[w][4 * g + r][ni * 16 + cl] = (bf16)sc[ni][r];
    bf16x8 pf0 = *reinterpret_cast<const bf16x8*>(&Ps[w][cl][g * 8]);
    bf16x8 pf1 = *reinterpret_cast<const bf16x8*>(&Ps[w][cl][g * 8 + 32]);

    // O += P * V   (V^T tile, identical lane mapping)
#pragma unroll
    for (int di = 0; di < 4; ++di) {
      bf16x8 v0 = *reinterpret_cast<const bf16x8*>(&Vt[di * 16 + cl][g * 8]);
      bf16x8 v1 = *reinterpret_cast<const bf16x8*>(&Vt[di * 16 + cl][g * 8 + 32]);
      o[di] = mfma16(pf0, v0, o[di]);
      o[di] = mfma16(pf1, v1, o[di]);
    }
    __syncthreads();
  }

  // epilogue: write x[t*B+b][h*64+d] bf16
  int b = bh / NH, h = bh % NH;
#pragma unroll
  for (int di = 0; di < 4; ++di)
#pragma unroll
    for (int r = 0; r < 4; ++r) {
      int t = qrow0 + 4 * g + r;
      float val = o[di][r] / drow[r];
      xo[(size_t)(t * BSZ + b) * EDIM + h * HD + di * 16 + cl] = (bf16)val;
    }
}

extern "C" void kernel_launch(void* const* d_in, const int* in_sizes, int n_in,
                              void* d_out, int out_size, void* d_ws, size_t ws_size,
                              hipStream_t stream) {
  const float* query = (const float*)d_in[0];
  const float* mask  = (const float*)d_in[1];
  const float* win   = (const float*)d_in[2];
  const float* bin   = (const float*)d_in[3];
  const float* wout  = (const float*)d_in[4];
  const float* bout  = (const float*)d_in[5];
  (void)in_sizes; (void)n_in; (void)out_size; (void)ws_size;

  char* ws = (char*)d_ws;
  float* ct = (float*)(ws + CT_OFF);
  float* st = (float*)(ws + ST_OFF);
  bf16* qb  = (bf16*)(ws + Q_OFF);
  bf16* kb  = (bf16*)(ws + KB_OFF);
  bf16* vb  = (bf16*)(ws + V_OFF);
  bf16* xb  = (bf16*)(ws + X_OFF);
  float* out = (float*)d_out;

  rope_tab_kernel<<<dim3((TLEN * 32) / 256), dim3(256), 0, stream>>>(ct, st);

  gemm_bt<0><<<dim3(3 * EDIM / 128, TLEN * BSZ / 128), dim3(256), 0, stream>>>(
      query, nullptr, win, bin, ct, st, qb, kb, vb, nullptr, 3 * EDIM, EDIM);

  attn_kernel<<<dim3(TLEN / 64, BSZ * NH), dim3(256), 0, stream>>>(qb, kb, vb, mask, xb);

  gemm_bt<1><<<dim3(EDIM / 128, TLEN * BSZ / 128), dim3(256), 0, stream>>>(
      nullptr, xb, wout, bout, nullptr, nullptr, nullptr, nullptr, nullptr, out, EDIM, EDIM);
}

// Round 2
// 360.975 us; speedup vs baseline: 1.2236x; 1.2236x over previous
//
#include <hip/hip_runtime.h>
#include <math.h>

#define TLEN 2048
#define BSZ  4
#define EDIM 768
#define NH   12
#define HD   64
#define NBH  (BSZ * NH)

typedef __bf16 bf16;
typedef __bf16 bf16x8 __attribute__((ext_vector_type(8)));
typedef float  f32x4  __attribute__((ext_vector_type(4)));
typedef unsigned int uint;

__device__ __forceinline__ f32x4 mfma16(bf16x8 a, bf16x8 b, f32x4 c) {
  return __builtin_amdgcn_mfma_f32_16x16x32_bf16(a, b, c, 0, 0, 0);
}

// async global->LDS 16B (dest = wave-uniform base + lane*16; source per-lane)
#define GLD16(gp, lp)                                                          \
  __builtin_amdgcn_global_load_lds(                                            \
      (const __attribute__((address_space(1))) uint32_t*)(gp),                 \
      (__attribute__((address_space(3))) uint32_t*)(lp), 16, 0, 0)

// swizzled LDS fragment read: tile rows of 128B, XOR bits 4-6 with row&7
__device__ __forceinline__ bf16x8 ldsfrag(const bf16* t, int row, int kb) {
  return *reinterpret_cast<const bf16x8*>(
      (const char*)t + row * 128 + (kb ^ ((row & 7) << 4)));
}

// ---------------- workspace layout (bytes) ----------------
#define CT_OFF   0x0u
#define ST_OFF   0x40000u
#define FLG_OFF  0x80000u
#define AQ_OFF   0x100000u   // query bf16; reused as VT after gemm0
#define VT_OFF   0x100000u
#define QB_OFF   0xD00000u
#define KB_OFF   0x1900000u
#define VB_OFF   0x2500000u  // reused as XB after vtrans
#define XB_OFF   0x2500000u
#define WI_OFF   0x3100000u
#define WO_OFF   0x3460000u

// ---------------- RoPE tables (fp64 for accurate large-arg sin) ----------------
__global__ void rope_tab_kernel(float* __restrict__ ct, float* __restrict__ st) {
  int i = blockIdx.x * 256 + threadIdx.x;  // grid exactly TLEN*32
  int t = i >> 5, j = i & 31;
  double ang = (double)t * pow(10000.0, -(double)j / 32.0);
  st[i] = (float)sin(ang);
  ct[i] = (float)cos(ang);
}

// ---------------- fp32 -> bf16 bulk convert (query, both weights) -------------
#define QN8  786432   // 2048*4*768/8
#define WIN8 221184   // 2304*768/8
#define WON8 73728    // 768*768/8

__device__ __forceinline__ void cvt8(const float* __restrict__ s,
                                     bf16* __restrict__ d, int i) {
  const float4* sp = reinterpret_cast<const float4*>(s) + (size_t)i * 2;
  float4 a = sp[0], b = sp[1];
  bf16x8 o;
  o[0] = (bf16)a.x; o[1] = (bf16)a.y; o[2] = (bf16)a.z; o[3] = (bf16)a.w;
  o[4] = (bf16)b.x; o[5] = (bf16)b.y; o[6] = (bf16)b.z; o[7] = (bf16)b.w;
  reinterpret_cast<bf16x8*>(d)[i] = o;
}

__global__ __launch_bounds__(256) void prep_cvt_kernel(
    const float* __restrict__ q, bf16* __restrict__ qo,
    const float* __restrict__ wi, bf16* __restrict__ wio,
    const float* __restrict__ wo, bf16* __restrict__ woo) {
  int i = blockIdx.x * 256 + threadIdx.x;
  if (i < QN8) { cvt8(q, qo, i); return; }
  int j = i - QN8;
  if (j < WIN8) { cvt8(wi, wio, j); return; }
  int k = j - WIN8;
  if (k < WON8) cvt8(wo, woo, k);
}

// ---------------- mask tile nonzero flags (64x64 tiles) ----------------
__global__ __launch_bounds__(256) void maskflag_kernel(
    const float* __restrict__ mask, uint* __restrict__ flags) {
  int tile = blockIdx.x;            // 0..1023
  int ty = tile >> 5, tx = tile & 31;
  int tid = threadIdx.x;
  uint acc = 0;
#pragma unroll
  for (int i = 0; i < 4; ++i) {
    int c = tid + 256 * i;          // float4 chunk within tile
    int rr = c >> 4, cc = (c & 15) * 4;
    float4 v = *reinterpret_cast<const float4*>(
        mask + (size_t)(ty * 64 + rr) * TLEN + tx * 64 + cc);
    acc |= __float_as_uint(v.x) | __float_as_uint(v.y) |
           __float_as_uint(v.z) | __float_as_uint(v.w);
  }
  unsigned long long b = __ballot(acc != 0);
  __shared__ uint red[4];
  if ((tid & 63) == 0) red[tid >> 6] = (b != 0ull) ? 1u : 0u;
  __syncthreads();
  if (tid == 0) flags[tile] = red[0] | red[1] | red[2] | red[3];
}

// ---------------- V transpose: [bh][t][d] -> [bh][d][t], register 8x8 ---------
__global__ __launch_bounds__(256) void vtrans_kernel(const bf16* __restrict__ v,
                                                     bf16* __restrict__ vt) {
  int w = threadIdx.x >> 6, lane = threadIdx.x & 63;
  int bh = blockIdx.y;
  int t0 = (blockIdx.x * 4 + w) * 64;
  const bf16* src = v + ((size_t)bh * TLEN + t0) * HD;
  bf16* dst = vt + (size_t)bh * HD * TLEN + t0;
  int d0 = (lane & 7) * 8, tr = (lane >> 3) * 8;
  bf16x8 in[8];
#pragma unroll
  for (int r = 0; r < 8; ++r)
    in[r] = *reinterpret_cast<const bf16x8*>(src + (size_t)(tr + r) * HD + d0);
  bf16x8 out[8];
#pragma unroll
  for (int j = 0; j < 8; ++j)
#pragma unroll
    for (int r = 0; r < 8; ++r) out[j][r] = in[r][j];
#pragma unroll
  for (int j = 0; j < 8; ++j)
    *reinterpret_cast<bf16x8*>(dst + (size_t)(d0 + j) * TLEN + tr) = out[j];
}

// ---------------- GEMM C = A * B^T (+bias), bf16 in, 128x128 tile, BK=64 ------
// MODE 0: A = query bf16 [8192][768]; B = in_proj_w bf16 [2304][768];
//         epilogue: split q/k/v, RoPE q,k, fold 1/8 into q -> bf16 [B][H][T][HD]
// MODE 1: A = attn-out bf16 [8192][768]; B = out_proj_w bf16 [768][768];
//         epilogue: +bias -> fp32 out
template <int MODE>
__global__ __launch_bounds__(256) void gemm_bt(
    const bf16* __restrict__ A, const bf16* __restrict__ B,
    const float* __restrict__ bias,
    const float* __restrict__ ct, const float* __restrict__ st,
    bf16* __restrict__ qo, bf16* __restrict__ ko, bf16* __restrict__ vo,
    float* __restrict__ fo) {
  constexpr int K = EDIM;
  __shared__ __align__(16) bf16 As[128 * 64];
  __shared__ __align__(16) bf16 Bs[128 * 64];
  int tid = threadIdx.x;
  int lane = tid & 63, w = tid >> 6;
  int wr = w >> 1, wc = w & 1;
  int g = lane >> 4, cl = lane & 15;
  int bm = blockIdx.y, bn = blockIdx.x;
  int lrow = lane >> 3;
  int colb = ((lane & 7) ^ lrow) << 4;   // inverse-swizzled source byte col
  const char* Abase = (const char*)(A + (size_t)bm * 128 * K);
  const char* Bbase = (const char*)(B + (size_t)bn * 128 * K);

  f32x4 acc[4][4] = {};

  for (int kt = 0; kt < K; kt += 64) {
#pragma unroll
    for (int i = 0; i < 4; ++i) {
      int qi = w * 4 + i;
      int row = qi * 8 + lrow;
      GLD16(Abase + (size_t)row * (K * 2) + kt * 2 + colb, As + qi * 512 + lane * 8);
      GLD16(Bbase + (size_t)row * (K * 2) + kt * 2 + colb, Bs + qi * 512 + lane * 8);
    }
    __syncthreads();
#pragma unroll
    for (int kk = 0; kk < 2; ++kk) {
      bf16x8 af[4], bfr[4];
#pragma unroll
      for (int mi = 0; mi < 4; ++mi)
        af[mi] = ldsfrag(As, wr * 64 + mi * 16 + cl, kk * 64 + g * 16);
#pragma unroll
      for (int ni = 0; ni < 4; ++ni)
        bfr[ni] = ldsfrag(Bs, wc * 64 + ni * 16 + cl, kk * 64 + g * 16);
#pragma unroll
      for (int mi = 0; mi < 4; ++mi)
#pragma unroll
        for (int ni = 0; ni < 4; ++ni)
          acc[mi][ni] = mfma16(af[mi], bfr[ni], acc[mi][ni]);
    }
    __syncthreads();
  }

  if (MODE == 0) {
#pragma unroll
    for (int mi = 0; mi < 4; ++mi) {
      int mbase = bm * 128 + wr * 64 + mi * 16 + 4 * g;  // rows mbase..mbase+3
      int t = mbase >> 2;                                // b = r
#pragma unroll
      for (int ni = 0; ni < 4; ++ni) {
        int f = bn * 128 + wc * 64 + ni * 16 + cl;
        int sec = f / EDIM;
        int f0 = f - sec * EDIM;
        int h = f0 >> 6, d = f0 & 63;
        float bv = bias[f];
        float vals[4];
#pragma unroll
        for (int r = 0; r < 4; ++r) vals[r] = acc[mi][ni][r] + bv;
        if (sec < 2) {
          int j = d >> 1;
          float cv = ct[t * 32 + j], sv = st[t * 32 + j];
          bf16* dst = (sec == 0) ? qo : ko;
#pragma unroll
          for (int r = 0; r < 4; ++r) {
            float other = __shfl_xor(vals[r], 1);
            float rv = (d & 1) ? (vals[r] * cv + other * sv)
                               : (vals[r] * cv - other * sv);
            if (sec == 0) rv *= 0.125f;
            dst[(((size_t)r * NH + h) * TLEN + t) * HD + d] = (bf16)rv;
          }
        } else {
#pragma unroll
          for (int r = 0; r < 4; ++r)
            vo[(((size_t)r * NH + h) * TLEN + t) * HD + d] = (bf16)vals[r];
        }
      }
    }
  } else {
#pragma unroll
    for (int mi = 0; mi < 4; ++mi) {
      int mbase = bm * 128 + wr * 64 + mi * 16 + 4 * g;
#pragma unroll
      for (int ni = 0; ni < 4; ++ni) {
        int n = bn * 128 + wc * 64 + ni * 16 + cl;
        float bv = bias[n];
#pragma unroll
        for (int r = 0; r < 4; ++r)
          fo[(size_t)(mbase + r) * EDIM + n] = acc[mi][ni][r] + bv;
      }
    }
  }
}

// ---------------- flash attention: Q-tile 128 (wave=32 rows), KV-tile 64 ------
__global__ __launch_bounds__(256) void attn_kernel(
    const bf16* __restrict__ qa, const bf16* __restrict__ ka,
    const bf16* __restrict__ vt, const float* __restrict__ mask,
    const uint* __restrict__ flags, bf16* __restrict__ xo) {
  __shared__ __align__(16) bf16 Ks[64 * 64];
  __shared__ __align__(16) bf16 Vs[64 * 64];
  __shared__ __align__(16) bf16 Ps[4][32][72];
  int tid = threadIdx.x;
  int lane = tid & 63, w = tid >> 6;
  int g = lane >> 4, cl = lane & 15;
  int bh = blockIdx.y;
  int qrow0 = blockIdx.x * 128 + w * 32;
  int qblk = qrow0 >> 6;
  const bf16* qbh = qa + (size_t)bh * TLEN * HD;
  const char* kbase = (const char*)(ka + (size_t)bh * TLEN * HD);
  const char* vbase = (const char*)(vt + (size_t)bh * HD * TLEN);
  int lrow = lane >> 3;
  int colb = ((lane & 7) ^ lrow) << 4;

  // hoist Q fragments (1/8 scale folded in at in_proj)
  bf16x8 qf[2][2];
#pragma unroll
  for (int mi = 0; mi < 2; ++mi)
#pragma unroll
    for (int h = 0; h < 2; ++h)
      qf[mi][h] = *reinterpret_cast<const bf16x8*>(
          qbh + (size_t)(qrow0 + mi * 16 + cl) * HD + h * 32 + g * 8);

  f32x4 o[2][4] = {};
  float mrow[2][4], drow[2][4];
#pragma unroll
  for (int mi = 0; mi < 2; ++mi)
#pragma unroll
    for (int r = 0; r < 4; ++r) { mrow[mi][r] = -1e30f; drow[mi][r] = 0.f; }

  for (int stile = 0; stile < TLEN / 64; ++stile) {
    int s0 = stile * 64;
    // stage K [s][d] (contiguous 8KB) and V^T [d][s] tiles, swizzled source
#pragma unroll
    for (int i = 0; i < 2; ++i) {
      int qi = w * 2 + i;
      int row = qi * 8 + lrow;
      GLD16(kbase + (size_t)(s0 + row) * 128 + colb, Ks + qi * 512 + lane * 8);
      GLD16(vbase + (size_t)row * (TLEN * 2) + s0 * 2 + colb, Vs + qi * 512 + lane * 8);
    }
    __syncthreads();

    // S = Q K^T
    f32x4 sc[2][4];
#pragma unroll
    for (int ni = 0; ni < 4; ++ni) {
      bf16x8 k0 = ldsfrag(Ks, ni * 16 + cl, g * 16);
      bf16x8 k1 = ldsfrag(Ks, ni * 16 + cl, 64 + g * 16);
#pragma unroll
      for (int mi = 0; mi < 2; ++mi) {
        f32x4 z = {};
        z = mfma16(qf[mi][0], k0, z);
        z = mfma16(qf[mi][1], k1, z);
        sc[mi][ni] = z;
      }
    }

    // mask add only when the 64x64 mask tile has nonzeros
    if (flags[qblk * 32 + stile]) {
#pragma unroll
      for (int mi = 0; mi < 2; ++mi)
#pragma unroll
        for (int ni = 0; ni < 4; ++ni)
#pragma unroll
          for (int r = 0; r < 4; ++r)
            sc[mi][ni][r] += mask[(size_t)(qrow0 + mi * 16 + 4 * g + r) * TLEN +
                                  s0 + ni * 16 + cl];
    }

    // online softmax (rows: mi*16 + 4g + r; cols: ni*16 + cl)
    float pm[2][4];
#pragma unroll
    for (int mi = 0; mi < 2; ++mi)
#pragma unroll
      for (int r = 0; r < 4; ++r) {
        float m0 = fmaxf(fmaxf(sc[mi][0][r], sc[mi][1][r]),
                         fmaxf(sc[mi][2][r], sc[mi][3][r]));
#pragma unroll
        for (int off = 1; off < 16; off <<= 1) m0 = fmaxf(m0, __shfl_xor(m0, off));
        pm[mi][r] = m0;
      }
    float alpha[2][4];
#pragma unroll
    for (int mi = 0; mi < 2; ++mi)
#pragma unroll
      for (int r = 0; r < 4; ++r) {
        float mn = fmaxf(mrow[mi][r], pm[mi][r]);
        alpha[mi][r] = __expf(mrow[mi][r] - mn);
        mrow[mi][r] = mn;
      }
    float rs[2][4] = {};
#pragma unroll
    for (int mi = 0; mi < 2; ++mi)
#pragma unroll
      for (int ni = 0; ni < 4; ++ni)
#pragma unroll
        for (int r = 0; r < 4; ++r) {
          float p = __expf(sc[mi][ni][r] - mrow[mi][r]);
          sc[mi][ni][r] = p;
          rs[mi][r] += p;
        }
#pragma unroll
    for (int mi = 0; mi < 2; ++mi)
#pragma unroll
      for (int r = 0; r < 4; ++r) {
        float s = rs[mi][r];
#pragma unroll
        for (int off = 1; off < 16; off <<= 1) s += __shfl_xor(s, off);
        drow[mi][r] = drow[mi][r] * alpha[mi][r] + s;
      }
#pragma unroll
    for (int mi = 0; mi < 2; ++mi)
#pragma unroll
      for (int di = 0; di < 4; ++di)
#pragma unroll
        for (int r = 0; r < 4; ++r) o[mi][di][r] *= alpha[mi][r];

    // P -> LDS (wave-private strip), reload as A-fragments
#pragma unroll
    for (int mi = 0; mi < 2; ++mi)
#pragma unroll
      for (int ni = 0; ni < 4; ++ni)
#pragma unroll
        for (int r = 0; r < 4; ++r)
          Ps[w][mi * 16 + 4 * g + r][ni * 16 + cl] = (bf16)sc[mi][ni][r];
    bf16x8 pf[2][2];
#pragma unroll
    for (int mi = 0; mi < 2; ++mi)
#pragma unroll
      for (int h = 0; h < 2; ++h)
        pf[mi][h] = *reinterpret_cast<const bf16x8*>(
            &Ps[w][mi * 16 + cl][h * 32 + g * 8]);

    // O += P * V  (Vs holds V^T: rows d, k = s)
#pragma unroll
    for (int di = 0; di < 4; ++di) {
      bf16x8 v0 = ldsfrag(Vs, di * 16 + cl, g * 16);
      bf16x8 v1 = ldsfrag(Vs, di * 16 + cl, 64 + g * 16);
#pragma unroll
      for (int mi = 0; mi < 2; ++mi) {
        o[mi][di] = mfma16(pf[mi][0], v0, o[mi][di]);
        o[mi][di] = mfma16(pf[mi][1], v1, o[mi][di]);
      }
    }
    __syncthreads();
  }

  // epilogue: x[t*B+b][h*64+d]
  int b = bh / NH, h = bh % NH;
#pragma unroll
  for (int mi = 0; mi < 2; ++mi)
#pragma unroll
    for (int di = 0; di < 4; ++di)
#pragma unroll
      for (int r = 0; r < 4; ++r) {
        int t = qrow0 + mi * 16 + 4 * g + r;
        float val = o[mi][di][r] / drow[mi][r];
        xo[(size_t)(t * BSZ + b) * EDIM + h * HD + di * 16 + cl] = (bf16)val;
      }
}

extern "C" void kernel_launch(void* const* d_in, const int* in_sizes, int n_in,
                              void* d_out, int out_size, void* d_ws, size_t ws_size,
                              hipStream_t stream) {
  const float* query = (const float*)d_in[0];
  const float* mask  = (const float*)d_in[1];
  const float* win   = (const float*)d_in[2];
  const float* bin   = (const float*)d_in[3];
  const float* wout  = (const float*)d_in[4];
  const float* bout  = (const float*)d_in[5];
  (void)in_sizes; (void)n_in; (void)out_size; (void)ws_size;

  char* ws = (char*)d_ws;
  float* ct   = (float*)(ws + CT_OFF);
  float* st   = (float*)(ws + ST_OFF);
  uint*  flg  = (uint*)(ws + FLG_OFF);
  bf16*  aq   = (bf16*)(ws + AQ_OFF);
  bf16*  vtb  = (bf16*)(ws + VT_OFF);   // reuses AQ region (AQ dead after gemm0)
  bf16*  qb   = (bf16*)(ws + QB_OFF);
  bf16*  kb   = (bf16*)(ws + KB_OFF);
  bf16*  vb   = (bf16*)(ws + VB_OFF);
  bf16*  xb   = (bf16*)(ws + XB_OFF);   // reuses VB region (VB dead after vtrans)
  bf16*  wib  = (bf16*)(ws + WI_OFF);
  bf16*  wob  = (bf16*)(ws + WO_OFF);
  float* out  = (float*)d_out;

  rope_tab_kernel<<<dim3((TLEN * 32) / 256), dim3(256), 0, stream>>>(ct, st);
  prep_cvt_kernel<<<dim3((QN8 + WIN8 + WON8) / 256), dim3(256), 0, stream>>>(
      query, aq, win, wib, wout, wob);
  maskflag_kernel<<<dim3(1024), dim3(256), 0, stream>>>(mask, flg);

  gemm_bt<0><<<dim3(3 * EDIM / 128, TLEN * BSZ / 128), dim3(256), 0, stream>>>(
      aq, wib, bin, ct, st, qb, kb, vb, nullptr);

  vtrans_kernel<<<dim3(TLEN / 256, NBH), dim3(256), 0, stream>>>(vb, vtb);

  attn_kernel<<<dim3(TLEN / 128, NBH), dim3(256), 0, stream>>>(
      qb, kb, vtb, mask, flg, xb);

  gemm_bt<1><<<dim3(EDIM / 128, TLEN * BSZ / 128), dim3(256), 0, stream>>>(
      xb, wob, bout, nullptr, nullptr, nullptr, nullptr, nullptr, out);
}

// Round 3
// 280.183 us; speedup vs baseline: 1.5765x; 1.2884x over previous
//
#include <hip/hip_runtime.h>
#include <math.h>

#define TLEN 2048
#define BSZ  4
#define EDIM 768
#define NH   12
#define HD   64
#define NBH  (BSZ * NH)

typedef __bf16 bf16;
typedef __bf16 bf16x8 __attribute__((ext_vector_type(8)));
typedef float  f32x4  __attribute__((ext_vector_type(4)));
typedef unsigned int uint;

__device__ __forceinline__ f32x4 mfma16(bf16x8 a, bf16x8 b, f32x4 c) {
  return __builtin_amdgcn_mfma_f32_16x16x32_bf16(a, b, c, 0, 0, 0);
}

// async global->LDS 16B (dest = wave-uniform base + lane*16; source per-lane)
#define GLD16(gp, lp)                                                          \
  __builtin_amdgcn_global_load_lds(                                            \
      (const __attribute__((address_space(1))) uint32_t*)(gp),                 \
      (__attribute__((address_space(3))) uint32_t*)(lp), 16, 0, 0)

// swizzled LDS fragment read: tile rows of 128B, XOR bits 4-6 with row&7
__device__ __forceinline__ bf16x8 ldsfrag(const bf16* t, int row, int kb) {
  return *reinterpret_cast<const bf16x8*>(
      (const char*)t + row * 128 + (kb ^ ((row & 7) << 4)));
}

// ---------------- workspace layout (bytes) ----------------
#define CT_OFF   0x0u
#define ST_OFF   0x40000u
#define FLG_OFF  0x80000u
#define AQ_OFF   0x100000u   // query bf16; reused as VT after gemm0
#define VT_OFF   0x100000u
#define QB_OFF   0xD00000u
#define KB_OFF   0x1900000u
#define VB_OFF   0x2500000u  // reused as XB after vtrans
#define XB_OFF   0x2500000u
#define WI_OFF   0x3100000u
#define WO_OFF   0x3460000u

#define QN8  786432   // 2048*4*768/8
#define WIN8 221184   // 2304*768/8
#define WON8 73728    // 768*768/8

__device__ __forceinline__ void cvt8(const float* __restrict__ s,
                                     bf16* __restrict__ d, int i) {
  const float4* sp = reinterpret_cast<const float4*>(s) + (size_t)i * 2;
  float4 a = sp[0], b = sp[1];
  bf16x8 o;
  o[0] = (bf16)a.x; o[1] = (bf16)a.y; o[2] = (bf16)a.z; o[3] = (bf16)a.w;
  o[4] = (bf16)b.x; o[5] = (bf16)b.y; o[6] = (bf16)b.z; o[7] = (bf16)b.w;
  reinterpret_cast<bf16x8*>(d)[i] = o;
}

// ---------------- fused prep: rope tables + fp32->bf16 cvt + mask flags -------
// blocks [0,256): rope; [256,4480): cvt; [4480,5504): mask flags
__global__ __launch_bounds__(256) void prep_all_kernel(
    const float* __restrict__ q, bf16* __restrict__ qo,
    const float* __restrict__ wi, bf16* __restrict__ wio,
    const float* __restrict__ wo, bf16* __restrict__ woo,
    const float* __restrict__ mask, uint* __restrict__ flags,
    float* __restrict__ ct, float* __restrict__ st) {
  int bid = blockIdx.x;
  int tid = threadIdx.x;
  if (bid < 256) {
    int i = bid * 256 + tid;               // TLEN*32 table entries
    int t = i >> 5, j = i & 31;
    double ang = (double)t * pow(10000.0, -(double)j / 32.0);
    st[i] = (float)sin(ang);
    ct[i] = (float)cos(ang);
  } else if (bid < 4480) {
    int i = (bid - 256) * 256 + tid;
    if (i < QN8) { cvt8(q, qo, i); return; }
    int j = i - QN8;
    if (j < WIN8) { cvt8(wi, wio, j); return; }
    cvt8(wo, woo, j - WIN8);
  } else {
    int tile = bid - 4480;                 // 0..1023
    int ty = tile >> 5, tx = tile & 31;
    uint acc = 0;
#pragma unroll
    for (int i = 0; i < 4; ++i) {
      int c = tid + 256 * i;
      int rr = c >> 4, cc = (c & 15) * 4;
      float4 v = *reinterpret_cast<const float4*>(
          mask + (size_t)(ty * 64 + rr) * TLEN + tx * 64 + cc);
      acc |= __float_as_uint(v.x) | __float_as_uint(v.y) |
             __float_as_uint(v.z) | __float_as_uint(v.w);
    }
    unsigned long long b = __ballot(acc != 0);
    __shared__ uint red[4];
    if ((tid & 63) == 0) red[tid >> 6] = (b != 0ull) ? 1u : 0u;
    __syncthreads();
    if (tid == 0) flags[tile] = red[0] | red[1] | red[2] | red[3];
  }
}

// ---------------- V transpose: [bh][t][d] -> [bh][d][t], register 8x8 ---------
__global__ __launch_bounds__(256) void vtrans_kernel(const bf16* __restrict__ v,
                                                     bf16* __restrict__ vt) {
  int w = threadIdx.x >> 6, lane = threadIdx.x & 63;
  int bh = blockIdx.y;
  int t0 = (blockIdx.x * 4 + w) * 64;
  const bf16* src = v + ((size_t)bh * TLEN + t0) * HD;
  bf16* dst = vt + (size_t)bh * HD * TLEN + t0;
  int d0 = (lane & 7) * 8, tr = (lane >> 3) * 8;
  bf16x8 in[8];
#pragma unroll
  for (int r = 0; r < 8; ++r)
    in[r] = *reinterpret_cast<const bf16x8*>(src + (size_t)(tr + r) * HD + d0);
  bf16x8 out[8];
#pragma unroll
  for (int j = 0; j < 8; ++j)
#pragma unroll
    for (int r = 0; r < 8; ++r) out[j][r] = in[r][j];
#pragma unroll
  for (int j = 0; j < 8; ++j)
    *reinterpret_cast<bf16x8*>(dst + (size_t)(d0 + j) * TLEN + tr) = out[j];
}

// ---------------- GEMM C = A * B^T (+bias), bf16 in, 128x128 tile, BK=64 ------
template <int MODE>
__global__ __launch_bounds__(256) void gemm_bt(
    const bf16* __restrict__ A, const bf16* __restrict__ B,
    const float* __restrict__ bias,
    const float* __restrict__ ct, const float* __restrict__ st,
    bf16* __restrict__ qo, bf16* __restrict__ ko, bf16* __restrict__ vo,
    float* __restrict__ fo) {
  constexpr int K = EDIM;
  __shared__ __align__(16) bf16 As[128 * 64];
  __shared__ __align__(16) bf16 Bs[128 * 64];
  int tid = threadIdx.x;
  int lane = tid & 63, w = tid >> 6;
  int wr = w >> 1, wc = w & 1;
  int g = lane >> 4, cl = lane & 15;
  int bm = blockIdx.y, bn = blockIdx.x;
  int lrow = lane >> 3;
  int colb = ((lane & 7) ^ lrow) << 4;
  const char* Abase = (const char*)(A + (size_t)bm * 128 * K);
  const char* Bbase = (const char*)(B + (size_t)bn * 128 * K);

  f32x4 acc[4][4] = {};

  for (int kt = 0; kt < K; kt += 64) {
#pragma unroll
    for (int i = 0; i < 4; ++i) {
      int qi = w * 4 + i;
      int row = qi * 8 + lrow;
      GLD16(Abase + (size_t)row * (K * 2) + kt * 2 + colb, As + qi * 512 + lane * 8);
      GLD16(Bbase + (size_t)row * (K * 2) + kt * 2 + colb, Bs + qi * 512 + lane * 8);
    }
    __syncthreads();
#pragma unroll
    for (int kk = 0; kk < 2; ++kk) {
      bf16x8 af[4], bfr[4];
#pragma unroll
      for (int mi = 0; mi < 4; ++mi)
        af[mi] = ldsfrag(As, wr * 64 + mi * 16 + cl, kk * 64 + g * 16);
#pragma unroll
      for (int ni = 0; ni < 4; ++ni)
        bfr[ni] = ldsfrag(Bs, wc * 64 + ni * 16 + cl, kk * 64 + g * 16);
#pragma unroll
      for (int mi = 0; mi < 4; ++mi)
#pragma unroll
        for (int ni = 0; ni < 4; ++ni)
          acc[mi][ni] = mfma16(af[mi], bfr[ni], acc[mi][ni]);
    }
    __syncthreads();
  }

  if (MODE == 0) {
#pragma unroll
    for (int mi = 0; mi < 4; ++mi) {
      int mbase = bm * 128 + wr * 64 + mi * 16 + 4 * g;
      int t = mbase >> 2;
#pragma unroll
      for (int ni = 0; ni < 4; ++ni) {
        int f = bn * 128 + wc * 64 + ni * 16 + cl;
        int sec = f / EDIM;
        int f0 = f - sec * EDIM;
        int h = f0 >> 6, d = f0 & 63;
        float bv = bias[f];
        float vals[4];
#pragma unroll
        for (int r = 0; r < 4; ++r) vals[r] = acc[mi][ni][r] + bv;
        if (sec < 2) {
          int j = d >> 1;
          float cv = ct[t * 32 + j], sv = st[t * 32 + j];
          bf16* dst = (sec == 0) ? qo : ko;
#pragma unroll
          for (int r = 0; r < 4; ++r) {
            float other = __shfl_xor(vals[r], 1);
            float rv = (d & 1) ? (vals[r] * cv + other * sv)
                               : (vals[r] * cv - other * sv);
            if (sec == 0) rv *= 0.125f;
            dst[(((size_t)r * NH + h) * TLEN + t) * HD + d] = (bf16)rv;
          }
        } else {
#pragma unroll
          for (int r = 0; r < 4; ++r)
            vo[(((size_t)r * NH + h) * TLEN + t) * HD + d] = (bf16)vals[r];
        }
      }
    }
  } else {
#pragma unroll
    for (int mi = 0; mi < 4; ++mi) {
      int mbase = bm * 128 + wr * 64 + mi * 16 + 4 * g;
#pragma unroll
      for (int ni = 0; ni < 4; ++ni) {
        int n = bn * 128 + wc * 64 + ni * 16 + cl;
        float bv = bias[n];
#pragma unroll
        for (int r = 0; r < 4; ++r)
          fo[(size_t)(mbase + r) * EDIM + n] = acc[mi][ni][r] + bv;
      }
    }
  }
}

// ---------------- flash attention v3 ------------------------------------------
// 512 threads = 8 waves x 16 q-rows (Q-tile 128); KV tile 64, double-buffered
// via global_load_lds prefetch (1 barrier/tile). Softmax denominator via
// ones-column MFMA; defer-max (THR=8) skips reduce+rescale in steady state.
__global__ __launch_bounds__(512) void attn_kernel(
    const bf16* __restrict__ qa, const bf16* __restrict__ ka,
    const bf16* __restrict__ vt, const float* __restrict__ mask,
    const uint* __restrict__ flags, bf16* __restrict__ xo) {
  __shared__ __align__(16) bf16 Ks[2][4096];
  __shared__ __align__(16) bf16 Vs[2][4096];
  __shared__ __align__(16) bf16 Ps[8][16][72];
  int tid = threadIdx.x;
  int lane = tid & 63, w = tid >> 6;
  int g = lane >> 4, cl = lane & 15;
  int bh = blockIdx.y;
  int qrow0 = blockIdx.x * 128 + w * 16;
  const bf16* qbh = qa + (size_t)bh * TLEN * HD;
  const char* kbase = (const char*)(ka + (size_t)bh * TLEN * HD);
  const char* vbase = (const char*)(vt + (size_t)bh * HD * TLEN);
  int lrow = lane >> 3;
  int colb = ((lane & 7) ^ lrow) << 4;
  int sw = w & 3;              // staging sub-role: waves 0-3 K, 4-7 V^T

  // hoisted Q fragments (1/8 scale folded in at in_proj)
  bf16x8 qf[2];
#pragma unroll
  for (int h = 0; h < 2; ++h)
    qf[h] = *reinterpret_cast<const bf16x8*>(
        qbh + (size_t)(qrow0 + cl) * HD + h * 32 + g * 8);

  bf16x8 ones;
#pragma unroll
  for (int j = 0; j < 8; ++j) ones[j] = (bf16)1.0f;

  f32x4 o[5] = {};   // o[0..3] = output cols, o[4] = softmax denominator
  float mrow[4];
#pragma unroll
  for (int r = 0; r < 4; ++r) mrow[r] = -1e30f;

  // prologue: stage tile 0 into buffer 0
  {
#pragma unroll
    for (int i = 0; i < 2; ++i) {
      int qi = sw * 2 + i;
      int row = qi * 8 + lrow;
      if (w < 4)
        GLD16(kbase + (size_t)row * 128 + colb, &Ks[0][qi * 512 + lane * 8]);
      else
        GLD16(vbase + (size_t)row * (TLEN * 2) + colb, &Vs[0][qi * 512 + lane * 8]);
    }
  }
  __syncthreads();

  for (int stile = 0; stile < TLEN / 64; ++stile) {
    int cur = stile & 1;
    // prefetch next tile into the other buffer (lands during compute)
    if (stile + 1 < TLEN / 64) {
      int s1 = (stile + 1) * 64;
#pragma unroll
      for (int i = 0; i < 2; ++i) {
        int qi = sw * 2 + i;
        int row = qi * 8 + lrow;
        if (w < 4)
          GLD16(kbase + (size_t)(s1 + row) * 128 + colb,
                &Ks[cur ^ 1][qi * 512 + lane * 8]);
        else
          GLD16(vbase + (size_t)row * (TLEN * 2) + s1 * 2 + colb,
                &Vs[cur ^ 1][qi * 512 + lane * 8]);
      }
    }
    const bf16* Kc = Ks[cur];
    const bf16* Vc = Vs[cur];

    // S = Q K^T : rows (q) = 4g+r, cols (s) = ni*16+cl
    f32x4 sc[4];
#pragma unroll
    for (int ni = 0; ni < 4; ++ni) {
      bf16x8 k0 = ldsfrag(Kc, ni * 16 + cl, g * 16);
      bf16x8 k1 = ldsfrag(Kc, ni * 16 + cl, 64 + g * 16);
      f32x4 z = {};
      z = mfma16(qf[0], k0, z);
      z = mfma16(qf[1], k1, z);
      sc[ni] = z;
    }

    // mask add only when the 64x64 mask tile has nonzeros
    if (flags[(qrow0 >> 6) * 32 + stile]) {
#pragma unroll
      for (int ni = 0; ni < 4; ++ni)
#pragma unroll
        for (int r = 0; r < 4; ++r)
          sc[ni][r] += mask[(size_t)(qrow0 + 4 * g + r) * TLEN +
                            stile * 64 + ni * 16 + cl];
    }

    // defer-max: only reduce+rescale when local max grew past mrow + 8
    float ml[4];
#pragma unroll
    for (int r = 0; r < 4; ++r)
      ml[r] = fmaxf(fmaxf(sc[0][r], sc[1][r]), fmaxf(sc[2][r], sc[3][r]));
    bool ok = (ml[0] <= mrow[0] + 8.f) && (ml[1] <= mrow[1] + 8.f) &&
              (ml[2] <= mrow[2] + 8.f) && (ml[3] <= mrow[3] + 8.f);
    if (!__all(ok)) {
#pragma unroll
      for (int r = 0; r < 4; ++r) {
        float m0 = ml[r];
#pragma unroll
        for (int off = 1; off < 16; off <<= 1) m0 = fmaxf(m0, __shfl_xor(m0, off));
        float mn = fmaxf(mrow[r], m0);
        float al = __expf(mrow[r] - mn);
        mrow[r] = mn;
#pragma unroll
        for (int di = 0; di < 5; ++di) o[di][r] *= al;
      }
    }

    // P = exp(S - mrow) -> LDS (wave-private strip)
#pragma unroll
    for (int ni = 0; ni < 4; ++ni)
#pragma unroll
      for (int r = 0; r < 4; ++r)
        Ps[w][4 * g + r][ni * 16 + cl] = (bf16)__expf(sc[ni][r] - mrow[r]);
    bf16x8 pf0 = *reinterpret_cast<const bf16x8*>(&Ps[w][cl][g * 8]);
    bf16x8 pf1 = *reinterpret_cast<const bf16x8*>(&Ps[w][cl][32 + g * 8]);

    // O += P * V ; denominator via ones column
#pragma unroll
    for (int di = 0; di < 4; ++di) {
      bf16x8 v0 = ldsfrag(Vc, di * 16 + cl, g * 16);
      bf16x8 v1 = ldsfrag(Vc, di * 16 + cl, 64 + g * 16);
      o[di] = mfma16(pf0, v0, o[di]);
      o[di] = mfma16(pf1, v1, o[di]);
    }
    o[4] = mfma16(pf0, ones, o[4]);
    o[4] = mfma16(pf1, ones, o[4]);

    __syncthreads();   // prefetch drained (vmcnt 0) + buffer-reuse protection
  }

  // epilogue: x[t*B+b][h*64+d]
  int b = bh / NH, h = bh % NH;
#pragma unroll
  for (int di = 0; di < 4; ++di)
#pragma unroll
    for (int r = 0; r < 4; ++r) {
      int t = qrow0 + 4 * g + r;
      float val = o[di][r] / o[4][r];
      xo[(size_t)(t * BSZ + b) * EDIM + h * HD + di * 16 + cl] = (bf16)val;
    }
}

extern "C" void kernel_launch(void* const* d_in, const int* in_sizes, int n_in,
                              void* d_out, int out_size, void* d_ws, size_t ws_size,
                              hipStream_t stream) {
  const float* query = (const float*)d_in[0];
  const float* mask  = (const float*)d_in[1];
  const float* win   = (const float*)d_in[2];
  const float* bin   = (const float*)d_in[3];
  const float* wout  = (const float*)d_in[4];
  const float* bout  = (const float*)d_in[5];
  (void)in_sizes; (void)n_in; (void)out_size; (void)ws_size;

  char* ws = (char*)d_ws;
  float* ct   = (float*)(ws + CT_OFF);
  float* st   = (float*)(ws + ST_OFF);
  uint*  flg  = (uint*)(ws + FLG_OFF);
  bf16*  aq   = (bf16*)(ws + AQ_OFF);
  bf16*  vtb  = (bf16*)(ws + VT_OFF);   // reuses AQ region (AQ dead after gemm0)
  bf16*  qb   = (bf16*)(ws + QB_OFF);
  bf16*  kb   = (bf16*)(ws + KB_OFF);
  bf16*  vb   = (bf16*)(ws + VB_OFF);
  bf16*  xb   = (bf16*)(ws + XB_OFF);   // reuses VB region (VB dead after vtrans)
  bf16*  wib  = (bf16*)(ws + WI_OFF);
  bf16*  wob  = (bf16*)(ws + WO_OFF);
  float* out  = (float*)d_out;

  prep_all_kernel<<<dim3(5504), dim3(256), 0, stream>>>(
      query, aq, win, wib, wout, wob, mask, flg, ct, st);

  gemm_bt<0><<<dim3(3 * EDIM / 128, TLEN * BSZ / 128), dim3(256), 0, stream>>>(
      aq, wib, bin, ct, st, qb, kb, vb, nullptr);

  vtrans_kernel<<<dim3(TLEN / 256, NBH), dim3(256), 0, stream>>>(vb, vtb);

  attn_kernel<<<dim3(TLEN / 128, NBH), dim3(512), 0, stream>>>(
      qb, kb, vtb, mask, flg, xb);

  gemm_bt<1><<<dim3(EDIM / 128, TLEN * BSZ / 128), dim3(256), 0, stream>>>(
      xb, wob, bout, nullptr, nullptr, nullptr, nullptr, nullptr, out);
}